// Round 1
// 485.868 us; speedup vs baseline: 1.0025x; 1.0025x over previous
//
#include <hip/hip_runtime.h>
#include <hip/hip_bf16.h>

// Problem constants (fixed by reference)
#define OUT_F 4096
#define IN_F  4096
#define N_SUB 512
#define SUBD  8
#define M_DIM 8192   // 4*2048 rows of input
#define N_SPARSE 65536

typedef __bf16 bf16x8 __attribute__((ext_vector_type(8)));
typedef float floatx4 __attribute__((ext_vector_type(4)));

// ---------------------------------------------------------------------------
// Kernel 1: dequantize codebook -> bf16 weight [OUT_F][IN_F], with norms.
// ---------------------------------------------------------------------------
__global__ __launch_bounds__(256) void build_weight(
    const float* __restrict__ cb,      // [N_CODES][8]
    const int*   __restrict__ map,     // [OUT_F][N_SUB]
    const int*   __restrict__ sa,      // [IN_F]
    const float* __restrict__ rn,      // [IN_F] rowise (broadcast over columns)
    const float* __restrict__ cn,      // [OUT_F] colwise (broadcast over rows)
    __hip_bfloat16* __restrict__ W)    // [OUT_F][IN_F]
{
    int t  = blockIdx.x * blockDim.x + threadIdx.x;
    int o  = t >> 9;
    int j8 = t & (N_SUB - 1);
    int j  = j8 * SUBD;
    int code = map[o * N_SUB + j8];
    float cno = cn[o];
    float4 c0 = *(const float4*)(cb + code * SUBD);
    float4 c1 = *(const float4*)(cb + code * SUBD + 4);
    int4 s0 = *(const int4*)(sa + j);
    int4 s1 = *(const int4*)(sa + j + 4);
    bool contig = (s0.x == j)     & (s0.y == j + 1) & (s0.z == j + 2) &
                  (s0.w == j + 3) & (s1.x == j + 4) & (s1.y == j + 5) &
                  (s1.z == j + 6) & (s1.w == j + 7);
    if (contig) {
        float4 r0 = *(const float4*)(rn + j);
        float4 r1 = *(const float4*)(rn + j + 4);
        union { __hip_bfloat16 h[8]; uint4 u; } pk;
        pk.h[0] = __float2bfloat16(c0.x * r0.x * cno);
        pk.h[1] = __float2bfloat16(c0.y * r0.y * cno);
        pk.h[2] = __float2bfloat16(c0.z * r0.z * cno);
        pk.h[3] = __float2bfloat16(c0.w * r0.w * cno);
        pk.h[4] = __float2bfloat16(c1.x * r1.x * cno);
        pk.h[5] = __float2bfloat16(c1.y * r1.y * cno);
        pk.h[6] = __float2bfloat16(c1.z * r1.z * cno);
        pk.h[7] = __float2bfloat16(c1.w * r1.w * cno);
        *(uint4*)(W + (long)o * IN_F + j) = pk.u;
    } else {
        float c[8] = {c0.x, c0.y, c0.z, c0.w, c1.x, c1.y, c1.z, c1.w};
        int   s[8] = {s0.x, s0.y, s0.z, s0.w, s1.x, s1.y, s1.z, s1.w};
#pragma unroll
        for (int e = 0; e < SUBD; e++)
            W[(long)o * IN_F + s[e]] = __float2bfloat16(c[e] * rn[s[e]] * cno);
    }
}

// ---------------------------------------------------------------------------
// Kernel 2: sparse outlier override (after scaling, raw values).
// ---------------------------------------------------------------------------
__global__ __launch_bounds__(256) void sparse_scatter(
    const int*   __restrict__ idx,
    const float* __restrict__ sp,
    __hip_bfloat16* __restrict__ W, int n)
{
    int t = blockIdx.x * blockDim.x + threadIdx.x;
    if (t < n) W[idx[t]] = __float2bfloat16(sp[t]);
}

// ---------------------------------------------------------------------------
// Kernel 3: fp32 -> bf16 convert of the activation, 8 elems/thread.
// ---------------------------------------------------------------------------
__global__ __launch_bounds__(256) void cvt_bf16(
    const float* __restrict__ in, __hip_bfloat16* __restrict__ out, long n)
{
    long i = ((long)blockIdx.x * blockDim.x + threadIdx.x) * 8;
    if (i >= n) return;
    float4 f0 = *(const float4*)(in + i);
    float4 f1 = *(const float4*)(in + i + 4);
    union { __hip_bfloat16 h[8]; uint4 u; } pk;
    pk.h[0] = __float2bfloat16(f0.x); pk.h[1] = __float2bfloat16(f0.y);
    pk.h[2] = __float2bfloat16(f0.z); pk.h[3] = __float2bfloat16(f0.w);
    pk.h[4] = __float2bfloat16(f1.x); pk.h[5] = __float2bfloat16(f1.y);
    pk.h[6] = __float2bfloat16(f1.z); pk.h[7] = __float2bfloat16(f1.w);
    *(uint4*)(out + i) = pk.u;
}

// ---------------------------------------------------------------------------
// Kernel 4: 256x256-tile 8-phase bf16 GEMM with counted vmcnt (T3+T4+T5).
//   C[m][n] = sum_k A[m][k]*B[n][k] + bias[n]
// 8 waves (2M x 4N), per-wave 128x64 output = acc[8][4] of 16x16 frags.
// LDS 128 KiB: [buf:2][mat:2][256*64] bf16, XOR chunk-swizzle (row&7) kept
// from the 128^2 kernel (0 bank conflicts), applied on the pre-swizzled
// global source since global_load_lds writes linearly.
//
// Per K-tile t (4 phases; quadrant Q(mq,nq) = mq half of A-rows x nq half
// of B-rows, all of K=64; 16 MFMA per phase):
//   ph0 Q(0,0): ds_read af0,bf0      ; stage A-half1(t+1) -> buf nxt
//   ph1 Q(0,1): ds_read bf1          ; stage B-half1(t+1) -> buf nxt
//   ph2 Q(1,0): ds_read af1          ; stage A-half0(t+2) -> buf cur (dead after ph1)
//   ph3 Q(1,1): (all frags in regs)  ; stage B-half0(t+2) -> buf cur (dead after ph2)
//   ... s_waitcnt vmcnt(4) at tile boundary ONLY (2 half-tiles in flight).
// Half-tile regions are exactly the quadrant-read regions:
//   A half h = rows [h*64,h*64+64) u [128+h*64, +64)        (WARPS_M=2)
//   B half h = rows {g*64+h*32 .. +32 | g=0..3}             (WARPS_N=4)
// Tail staging clamps source k to 0 (valid dummy loads into dead regions).
// ---------------------------------------------------------------------------
#define BM 256
#define BN 256
#define BK 64
#define NT (IN_F / BK)   // 64 K-tiles

__device__ __forceinline__ void gl2lds16(const __hip_bfloat16* g, __hip_bfloat16* l)
{
    __builtin_amdgcn_global_load_lds(
        (const __attribute__((address_space(1))) unsigned int*)g,
        (__attribute__((address_space(3))) unsigned int*)l,
        16, 0, 0);
}

// Stage A half h of one K-tile: 2 x global_load_lds per thread.
// gr = j*128 + h*64 + u ; source chunk pre-swizzled by gr&7.
__device__ __forceinline__ void stage_half_A(
    const __hip_bfloat16* __restrict__ Ab, int row0, int kk,
    __hip_bfloat16* lds, int h, int u, int p)
{
#pragma unroll
    for (int j = 0; j < 2; j++) {
        const int gr = j * 128 + h * 64 + u;
        gl2lds16(Ab + (size_t)(row0 + gr) * IN_F + kk + ((p ^ (gr & 7)) << 3),
                 lds + gr * BK + p * 8);
    }
}

// Stage B half h: region rows {g*64 + h*32 .. +32}.
__device__ __forceinline__ void stage_half_B(
    const __hip_bfloat16* __restrict__ Bb, int row0, int kk,
    __hip_bfloat16* lds, int h, int u, int p)
{
#pragma unroll
    for (int j = 0; j < 2; j++) {
        const int rl = j * 64 + u;
        const int gr = (rl & 31) + h * 32 + ((rl >> 5) << 6);
        gl2lds16(Bb + (size_t)(row0 + gr) * IN_F + kk + ((p ^ (gr & 7)) << 3),
                 lds + gr * BK + p * 8);
    }
}

__device__ __forceinline__ void load_af(bf16x8 (&dst)[4][2],
    const __hip_bfloat16* sbuf, int rowbase, const int (&koff)[2])
{
#pragma unroll
    for (int i = 0; i < 4; i++) {
        const __hip_bfloat16* rp = sbuf + (rowbase + i * 16) * BK;
        dst[i][0] = *(const bf16x8*)(rp + koff[0]);
        dst[i][1] = *(const bf16x8*)(rp + koff[1]);
    }
}

__device__ __forceinline__ void load_bf(bf16x8 (&dst)[2][2],
    const __hip_bfloat16* sbuf, int rowbase, const int (&koff)[2])
{
#pragma unroll
    for (int n2 = 0; n2 < 2; n2++) {
        const __hip_bfloat16* rp = sbuf + (rowbase + n2 * 16) * BK;
        dst[n2][0] = *(const bf16x8*)(rp + koff[0]);
        dst[n2][1] = *(const bf16x8*)(rp + koff[1]);
    }
}

template<int MQ, int NQ>
__device__ __forceinline__ void mfma_quad(floatx4 (&acc)[8][4],
    const bf16x8 (&af)[4][2], const bf16x8 (&bfr)[2][2])
{
#pragma unroll
    for (int i = 0; i < 4; i++)
#pragma unroll
        for (int n2 = 0; n2 < 2; n2++)
#pragma unroll
            for (int ks = 0; ks < 2; ks++)
                acc[MQ * 4 + i][NQ * 2 + n2] =
                    __builtin_amdgcn_mfma_f32_16x16x32_bf16(
                        af[i][ks], bfr[n2][ks], acc[MQ * 4 + i][NQ * 2 + n2],
                        0, 0, 0);
}

__global__ __launch_bounds__(512, 2) void gemm256_8ph(
    const __hip_bfloat16* __restrict__ A,   // [M][K]
    const __hip_bfloat16* __restrict__ B,   // [N][K]
    const float* __restrict__ bias,         // [N]
    float* __restrict__ C)                  // [M][N]
{
    __shared__ __hip_bfloat16 sm[2][2][BM * BK];   // 128 KiB

    const int tid  = threadIdx.x;
    const int wave = tid >> 6;
    const int lane = tid & 63;
    const int l16  = lane & 15;
    const int quad = lane >> 4;
    const int u    = wave * 8 + (lane >> 3);   // 0..63 staging row-slot
    const int p    = lane & 7;                 // staging chunk pos

    // bijective XCD swizzle (512 wgs, 512 % 8 == 0)
    const int wg  = blockIdx.x;
    const int swz = (wg & 7) * 64 + (wg >> 3);
    const int bm  = swz >> 4;    // 32 M-tiles
    const int bn  = swz & 15;    // 16 N-tiles
    const int rowA0 = bm * BM;
    const int rowB0 = bn * BN;

    const int wm = (wave >> 2) * 128;   // wave A-row offset
    const int wn = (wave & 3) * 64;     // wave B-row offset

    floatx4 acc[8][4] = {};
    const int koff[2] = { ((0 * 4 + quad) ^ p) * 8, ((1 * 4 + quad) ^ p) * 8 };

    // ---- prologue: Al(0) Bl(0) Ah(0) Bh(0) Al(1) Bl(1); keep newest 2 in flight
    stage_half_A(A, rowA0, 0,  &sm[0][0][0], 0, u, p);
    stage_half_B(B, rowB0, 0,  &sm[0][1][0], 0, u, p);
    stage_half_A(A, rowA0, 0,  &sm[0][0][0], 1, u, p);
    stage_half_B(B, rowB0, 0,  &sm[0][1][0], 1, u, p);
    stage_half_A(A, rowA0, BK, &sm[1][0][0], 0, u, p);
    stage_half_B(B, rowB0, BK, &sm[1][1][0], 0, u, p);
    asm volatile("s_waitcnt vmcnt(4)" ::: "memory");
    __builtin_amdgcn_s_barrier();

    bf16x8 af0[4][2], af1[4][2], bf0[2][2], bf1[2][2];

    int kt = 0;
    for (int t = 0; t < NT; ++t) {
        const int cur = t & 1;
        __hip_bfloat16* sAc = &sm[cur][0][0];
        __hip_bfloat16* sBc = &sm[cur][1][0];
        __hip_bfloat16* sAn = &sm[cur ^ 1][0][0];
        __hip_bfloat16* sBn = &sm[cur ^ 1][1][0];
        int k1 = kt + BK;     if (k1 >= IN_F) k1 = 0;   // tile t+1 src (clamped)
        int k2 = kt + 2 * BK; if (k2 >= IN_F) k2 = 0;   // tile t+2 src (clamped)

        // ---------- phase 0: Q(0,0)
        load_af(af0, sAc, wm + l16, koff);
        load_bf(bf0, sBc, wn + l16, koff);
        stage_half_A(A, rowA0, k1, sAn, 1, u, p);       // Ah(t+1)
        __builtin_amdgcn_s_barrier();
        asm volatile("s_waitcnt lgkmcnt(0)" ::: "memory");
        __builtin_amdgcn_s_setprio(1);
        mfma_quad<0, 0>(acc, af0, bf0);
        __builtin_amdgcn_s_setprio(0);
        __builtin_amdgcn_s_barrier();

        // ---------- phase 1: Q(0,1)
        load_bf(bf1, sBc, wn + 32 + l16, koff);
        stage_half_B(B, rowB0, k1, sBn, 1, u, p);       // Bh(t+1)
        __builtin_amdgcn_s_barrier();
        asm volatile("s_waitcnt lgkmcnt(0)" ::: "memory");
        __builtin_amdgcn_s_setprio(1);
        mfma_quad<0, 1>(acc, af0, bf1);
        __builtin_amdgcn_s_setprio(0);
        __builtin_amdgcn_s_barrier();

        // ---------- phase 2: Q(1,0)   (A-low of cur is dead -> stage into it)
        load_af(af1, sAc, wm + 64 + l16, koff);
        stage_half_A(A, rowA0, k2, sAc, 0, u, p);       // Al(t+2)
        __builtin_amdgcn_s_barrier();
        asm volatile("s_waitcnt lgkmcnt(0)" ::: "memory");
        __builtin_amdgcn_s_setprio(1);
        mfma_quad<1, 0>(acc, af1, bf0);
        __builtin_amdgcn_s_setprio(0);
        __builtin_amdgcn_s_barrier();

        // ---------- phase 3: Q(1,1)   (B-low of cur is dead -> stage into it)
        stage_half_B(B, rowB0, k2, sBc, 0, u, p);       // Bl(t+2)
        __builtin_amdgcn_s_barrier();
        __builtin_amdgcn_s_setprio(1);
        mfma_quad<1, 1>(acc, af1, bf1);
        __builtin_amdgcn_s_setprio(0);
        asm volatile("s_waitcnt vmcnt(4)" ::: "memory"); // counted, never 0 mid-loop
        __builtin_amdgcn_s_barrier();

        kt += BK;
    }
    // drain dummy tail loads before LDS goes away / epilogue
    asm volatile("s_waitcnt vmcnt(0)" ::: "memory");

    // epilogue: C/D layout col=lane&15, row=quad*4+reg   [measured m89]
#pragma unroll
    for (int mt = 0; mt < 8; mt++) {
        const int row = rowA0 + wm + mt * 16 + quad * 4;
#pragma unroll
        for (int nt = 0; nt < 4; nt++) {
            const int col = rowB0 + wn + nt * 16 + l16;
            const float bv = bias[col];
            float* cp = C + (size_t)row * OUT_F + col;
#pragma unroll
            for (int r = 0; r < 4; r++)
                cp[(size_t)r * OUT_F] = acc[mt][nt][r] + bv;
        }
    }
}

// ---------------------------------------------------------------------------
// launch
// ---------------------------------------------------------------------------
extern "C" void kernel_launch(void* const* d_in, const int* in_sizes, int n_in,
                              void* d_out, int out_size, void* d_ws, size_t ws_size,
                              hipStream_t stream)
{
    const float* input = (const float*)d_in[0];   // [4,2048,4096] fp32
    const float* cb    = (const float*)d_in[1];   // [4096,8]
    const int*   map   = (const int*)  d_in[2];   // [4096,512]
    const int*   sa    = (const int*)  d_in[3];   // [4096]
    const float* rn    = (const float*)d_in[4];   // [4096]
    const float* cn    = (const float*)d_in[5];   // [4096]
    const int*   sidx  = (const int*)  d_in[6];   // [65536]
    const float* sp    = (const float*)d_in[7];   // [65536]
    const float* bias  = (const float*)d_in[8];   // [4096]
    float* out = (float*)d_out;                   // [8192,4096] fp32

    // workspace layout: W bf16 (32 MB) | A bf16 (64 MB)
    __hip_bfloat16* W  = (__hip_bfloat16*)d_ws;
    __hip_bfloat16* Ab = (__hip_bfloat16*)((char*)d_ws + (size_t)OUT_F * IN_F * 2);

    // 1) dequant weight
    build_weight<<<(OUT_F * N_SUB) / 256, 256, 0, stream>>>(cb, map, sa, rn, cn, W);
    // 2) sparse override
    sparse_scatter<<<N_SPARSE / 256, 256, 0, stream>>>(sidx, sp, W, N_SPARSE);
    // 3) activation fp32 -> bf16
    const long n_act = (long)M_DIM * IN_F;
    cvt_bf16<<<(int)(n_act / 8 / 256), 256, 0, stream>>>(input, Ab, n_act);
    // 4) GEMM + bias (256^2 tile, 8-phase, 512 wgs)
    gemm256_8ph<<<dim3((M_DIM / BM) * (OUT_F / BN)), 512, 0, stream>>>(Ab, W, bias, out);
}